// Round 3
// baseline (207.372 us; speedup 1.0000x reference)
//
#include <hip/hip_runtime.h>
#include <hip/hip_bf16.h>
#include <math.h>

#define NN 50000
#define DD 128
#define ALPHA 0.1f
#define BETA 0.5f

// ---------------------------------------------------------------------------
// Kernel 1: build CSR row pointer from sorted edge_row.
// ---------------------------------------------------------------------------
__global__ void build_rowptr(const int* __restrict__ edge_row, int E,
                             int* __restrict__ rp) {
    int e = blockIdx.x * blockDim.x + threadIdx.x;
    if (e > E) return;
    if (e == 0) {
        int r0 = edge_row[0];
        for (int r = 0; r <= r0; ++r) rp[r] = 0;
    } else if (e == E) {
        int rl = edge_row[E - 1];
        for (int r = rl + 1; r <= NN; ++r) rp[r] = E;
    } else {
        int rprev = edge_row[e - 1];
        int rcur  = edge_row[e];
        for (int r = rprev + 1; r <= rcur; ++r) rp[r] = e;
    }
}

// ---------------------------------------------------------------------------
// Kernel 2: aggregation only. One wave per row, no LDS, no barriers.
//   support[r] = 0.9 * sum_e val[e]*h[col[e]] + 0.1 * h0[r]  -> written to io
// Wave layout: halves p=0/1 take alternating edges; lane li (0..31) owns
// features li*4..li*4+3 (float4). 4-way unroll -> 8 edges / 4 gathers in
// flight per lane, straight-line (clamped+masked) so loads batch.
// ---------------------------------------------------------------------------
__global__ __launch_bounds__(256, 6) void agg_kernel(
    const float* __restrict__ h, const float* __restrict__ h0,
    const int* __restrict__ edge_col, const float* __restrict__ edge_vals,
    const int* __restrict__ rp, float* __restrict__ io)
{
    const int wave = threadIdx.x >> 6;
    const int lane = threadIdx.x & 63;
    const int p    = lane >> 5;
    const int li   = lane & 31;
    const int r    = blockIdx.x * 4 + wave;
    if (r >= NN) return;

    const int e0 = rp[r], e1 = rp[r + 1];

    float4 A[4];
    #pragma unroll
    for (int u = 0; u < 4; ++u) A[u] = make_float4(0.f, 0.f, 0.f, 0.f);

    for (int eb = e0; eb < e1; eb += 8) {
        #pragma unroll
        for (int u = 0; u < 4; ++u) {
            const int e  = eb + 2 * u + p;
            const int ee = min(e, e1 - 1);
            const int   c = edge_col[ee];
            const float v = (e < e1) ? edge_vals[ee] : 0.0f;
            const float4 hv =
                *reinterpret_cast<const float4*>(h + (size_t)c * DD + li * 4);
            A[u].x = fmaf(v, hv.x, A[u].x);
            A[u].y = fmaf(v, hv.y, A[u].y);
            A[u].z = fmaf(v, hv.z, A[u].z);
            A[u].w = fmaf(v, hv.w, A[u].w);
        }
    }
    float4 s;
    s.x = (A[0].x + A[1].x) + (A[2].x + A[3].x);
    s.y = (A[0].y + A[1].y) + (A[2].y + A[3].y);
    s.z = (A[0].z + A[1].z) + (A[2].z + A[3].z);
    s.w = (A[0].w + A[1].w) + (A[2].w + A[3].w);
    s.x += __shfl_xor(s.x, 32);
    s.y += __shfl_xor(s.y, 32);
    s.z += __shfl_xor(s.z, 32);
    s.w += __shfl_xor(s.w, 32);

    if (p == 0) {
        const float4 h0v =
            *reinterpret_cast<const float4*>(h0 + (size_t)r * DD + li * 4);
        float4 sup;
        sup.x = fmaf(1.0f - ALPHA, s.x, ALPHA * h0v.x);
        sup.y = fmaf(1.0f - ALPHA, s.y, ALPHA * h0v.y);
        sup.z = fmaf(1.0f - ALPHA, s.z, ALPHA * h0v.z);
        sup.w = fmaf(1.0f - ALPHA, s.w, ALPHA * h0v.w);
        *reinterpret_cast<float4*>(io + (size_t)r * DD + li * 4) = sup;
    }
}

// ---------------------------------------------------------------------------
// Kernel 3: in-place linear+blend on io (= support on entry, out on exit).
//   out = theta*(support @ W.T + b) + (1-theta)*support
// 64-row tile, 512 threads. support staged bf16 in LDS; the fp32 values a
// thread stages are exactly its output fragment -> kept in regs for the
// epilogue (no re-read). LDS 52.2KB -> 3 blocks/CU.
// ---------------------------------------------------------------------------
#define RPB 64
#define SPADB 136   // bf16 pad: 272B rows = 17*16B (aligned, conflict-spread)
#define WPAD 136

__device__ __forceinline__ float bf16lo(unsigned u) {
    return __uint_as_float(u << 16);
}
__device__ __forceinline__ float bf16hi(unsigned u) {
    return __uint_as_float(u & 0xffff0000u);
}
__device__ __forceinline__ unsigned pkbf(float a, float b) {
    unsigned la = (unsigned)__bfloat16_as_ushort(__float2bfloat16(a));
    unsigned lb = (unsigned)__bfloat16_as_ushort(__float2bfloat16(b));
    return la | (lb << 16);
}

__global__ __launch_bounds__(512, 6) void lin_kernel(
    float* io, const float* __restrict__ W, const float* __restrict__ b,
    const int* __restrict__ lptr)
{
    __shared__ __hip_bfloat16 sA[RPB][SPADB];   // support bf16 (17.4 KB)
    __shared__ __hip_bfloat16 sWt[DD][WPAD];    // W^T bf16 (34.8 KB)

    const int tid = threadIdx.x;
    const int r0  = blockIdx.x * RPB;
    const int tr  = tid >> 4;   // 0..31 -> rows tr*2..+1
    const int tc  = tid & 15;   // 0..15 -> cols tc*8..+7

    const int lv = *lptr;
    const float theta  = logf(BETA / (float)lv + 1.0f);
    const float mtheta = 1.0f - theta;

    // --- stage W transposed (bf16) ---
    for (int i = tid * 4; i < DD * DD; i += 512 * 4) {
        const float4 w4 = *reinterpret_cast<const float4*>(W + i);
        const int o = i >> 7;
        const int k = i & 127;
        sWt[k + 0][o] = __float2bfloat16(w4.x);
        sWt[k + 1][o] = __float2bfloat16(w4.y);
        sWt[k + 2][o] = __float2bfloat16(w4.z);
        sWt[k + 3][o] = __float2bfloat16(w4.w);
    }

    // --- stage support tile; keep own fp32 fragment in regs ---
    float4 supr[2][2];
    #pragma unroll
    for (int i = 0; i < 2; ++i) {
        const int ri = tr * 2 + i;
        const int rr = r0 + ri;
        #pragma unroll
        for (int j4 = 0; j4 < 2; ++j4) {
            supr[i][j4] = (rr < NN)
                ? *reinterpret_cast<const float4*>(io + (size_t)rr * DD + tc * 8 + j4 * 4)
                : make_float4(0.f, 0.f, 0.f, 0.f);
        }
        uint4 pk;
        pk.x = pkbf(supr[i][0].x, supr[i][0].y);
        pk.y = pkbf(supr[i][0].z, supr[i][0].w);
        pk.z = pkbf(supr[i][1].x, supr[i][1].y);
        pk.w = pkbf(supr[i][1].z, supr[i][1].w);
        *reinterpret_cast<uint4*>(&sA[ri][tc * 8]) = pk;
    }
    __syncthreads();

    // --- GEMM: 2 rows x 8 cols per thread, fp32 accum ---
    float acc[2][8];
    #pragma unroll
    for (int i = 0; i < 2; ++i)
        #pragma unroll
        for (int j = 0; j < 8; ++j) acc[i][j] = 0.f;

    for (int k = 0; k < DD; k += 8) {
        const uint4 a0 = *reinterpret_cast<const uint4*>(&sA[tr * 2 + 0][k]);
        const uint4 a1 = *reinterpret_cast<const uint4*>(&sA[tr * 2 + 1][k]);
        float fa0[8], fa1[8];
        fa0[0] = bf16lo(a0.x); fa0[1] = bf16hi(a0.x);
        fa0[2] = bf16lo(a0.y); fa0[3] = bf16hi(a0.y);
        fa0[4] = bf16lo(a0.z); fa0[5] = bf16hi(a0.z);
        fa0[6] = bf16lo(a0.w); fa0[7] = bf16hi(a0.w);
        fa1[0] = bf16lo(a1.x); fa1[1] = bf16hi(a1.x);
        fa1[2] = bf16lo(a1.y); fa1[3] = bf16hi(a1.y);
        fa1[4] = bf16lo(a1.z); fa1[5] = bf16hi(a1.z);
        fa1[6] = bf16lo(a1.w); fa1[7] = bf16hi(a1.w);
        #pragma unroll
        for (int kk = 0; kk < 8; ++kk) {
            const uint4 wr = *reinterpret_cast<const uint4*>(&sWt[k + kk][tc * 8]);
            float w[8];
            w[0] = bf16lo(wr.x); w[1] = bf16hi(wr.x);
            w[2] = bf16lo(wr.y); w[3] = bf16hi(wr.y);
            w[4] = bf16lo(wr.z); w[5] = bf16hi(wr.z);
            w[6] = bf16lo(wr.w); w[7] = bf16hi(wr.w);
            #pragma unroll
            for (int j = 0; j < 8; ++j) {
                acc[0][j] = fmaf(fa0[kk], w[j], acc[0][j]);
                acc[1][j] = fmaf(fa1[kk], w[j], acc[1][j]);
            }
        }
    }

    // --- epilogue: blend with fp32 support from regs, write in place ---
    #pragma unroll
    for (int i = 0; i < 2; ++i) {
        const int rr = r0 + tr * 2 + i;
        if (rr >= NN) continue;
        #pragma unroll
        for (int j4 = 0; j4 < 2; ++j4) {
            const int cc = tc * 8 + j4 * 4;
            const float4 bv = *reinterpret_cast<const float4*>(&b[cc]);
            const float4 s  = supr[i][j4];
            float4 o4;
            o4.x = theta * (acc[i][j4 * 4 + 0] + bv.x) + mtheta * s.x;
            o4.y = theta * (acc[i][j4 * 4 + 1] + bv.y) + mtheta * s.y;
            o4.z = theta * (acc[i][j4 * 4 + 2] + bv.z) + mtheta * s.z;
            o4.w = theta * (acc[i][j4 * 4 + 3] + bv.w) + mtheta * s.w;
            *reinterpret_cast<float4*>(io + (size_t)rr * DD + cc) = o4;
        }
    }
}

extern "C" void kernel_launch(void* const* d_in, const int* in_sizes, int n_in,
                              void* d_out, int out_size, void* d_ws, size_t ws_size,
                              hipStream_t stream) {
    const float* h         = (const float*)d_in[0];
    const float* h0        = (const float*)d_in[1];
    const int*   edge_row  = (const int*)d_in[2];
    const int*   edge_col  = (const int*)d_in[3];
    const float* edge_vals = (const float*)d_in[4];
    const float* W         = (const float*)d_in[5];
    const float* b         = (const float*)d_in[6];
    const int*   lptr      = (const int*)d_in[7];
    const int E = in_sizes[2];

    int* rp = (int*)d_ws;  // N+1 ints (~200KB)
    float* io = (float*)d_out;

    build_rowptr<<<(E + 1 + 255) / 256, 256, 0, stream>>>(edge_row, E, rp);

    agg_kernel<<<(NN + 3) / 4, 256, 0, stream>>>(h, h0, edge_col, edge_vals, rp, io);

    lin_kernel<<<(NN + RPB - 1) / RPB, 512, 0, stream>>>(io, W, b, lptr);
}

// Round 4
// 116.752 us; speedup vs baseline: 1.7762x; 1.7762x over previous
//
#include <hip/hip_runtime.h>
#include <hip/hip_bf16.h>
#include <math.h>

#define NN 50000
#define DD 128
#define ALPHA 0.1f
#define BETA 0.5f

// ---------------------------------------------------------------------------
// Kernel 1: build CSR row pointer from sorted edge_row.
// ---------------------------------------------------------------------------
__global__ void build_rowptr(const int* __restrict__ edge_row, int E,
                             int* __restrict__ rp) {
    int e = blockIdx.x * blockDim.x + threadIdx.x;
    if (e > E) return;
    if (e == 0) {
        int r0 = edge_row[0];
        for (int r = 0; r <= r0; ++r) rp[r] = 0;
    } else if (e == E) {
        int rl = edge_row[E - 1];
        for (int r = rl + 1; r <= NN; ++r) rp[r] = E;
    } else {
        int rprev = edge_row[e - 1];
        int rcur  = edge_row[e];
        for (int r = rprev + 1; r <= rcur; ++r) rp[r] = e;
    }
}

// ---------------------------------------------------------------------------
// Kernel 2: aggregation only. One wave per row, no LDS, no barriers.
//   io[r] = 0.9 * sum_e val[e]*h[col[e]] + 0.1 * h0[r]
// Halves p=0/1 take alternating edges; lane li owns features li*4..+3.
// 4-way unroll -> 8 edges / 4 independent gathers in flight.
// ---------------------------------------------------------------------------
__global__ __launch_bounds__(256, 6) void agg_kernel(
    const float* __restrict__ h, const float* __restrict__ h0,
    const int* __restrict__ edge_col, const float* __restrict__ edge_vals,
    const int* __restrict__ rp, float* __restrict__ io)
{
    const int wave = threadIdx.x >> 6;
    const int lane = threadIdx.x & 63;
    const int p    = lane >> 5;
    const int li   = lane & 31;
    const int r    = blockIdx.x * 4 + wave;
    if (r >= NN) return;

    const int e0 = rp[r], e1 = rp[r + 1];

    float4 A[4];
    #pragma unroll
    for (int u = 0; u < 4; ++u) A[u] = make_float4(0.f, 0.f, 0.f, 0.f);

    for (int eb = e0; eb < e1; eb += 8) {
        #pragma unroll
        for (int u = 0; u < 4; ++u) {
            const int e  = eb + 2 * u + p;
            const int ee = min(e, e1 - 1);
            const int   c = edge_col[ee];
            const float v = (e < e1) ? edge_vals[ee] : 0.0f;
            const float4 hv =
                *reinterpret_cast<const float4*>(h + (size_t)c * DD + li * 4);
            A[u].x = fmaf(v, hv.x, A[u].x);
            A[u].y = fmaf(v, hv.y, A[u].y);
            A[u].z = fmaf(v, hv.z, A[u].z);
            A[u].w = fmaf(v, hv.w, A[u].w);
        }
    }
    float4 s;
    s.x = (A[0].x + A[1].x) + (A[2].x + A[3].x);
    s.y = (A[0].y + A[1].y) + (A[2].y + A[3].y);
    s.z = (A[0].z + A[1].z) + (A[2].z + A[3].z);
    s.w = (A[0].w + A[1].w) + (A[2].w + A[3].w);
    s.x += __shfl_xor(s.x, 32);
    s.y += __shfl_xor(s.y, 32);
    s.z += __shfl_xor(s.z, 32);
    s.w += __shfl_xor(s.w, 32);

    if (p == 0) {
        const float4 h0v =
            *reinterpret_cast<const float4*>(h0 + (size_t)r * DD + li * 4);
        float4 sup;
        sup.x = fmaf(1.0f - ALPHA, s.x, ALPHA * h0v.x);
        sup.y = fmaf(1.0f - ALPHA, s.y, ALPHA * h0v.y);
        sup.z = fmaf(1.0f - ALPHA, s.z, ALPHA * h0v.z);
        sup.w = fmaf(1.0f - ALPHA, s.w, ALPHA * h0v.w);
        *reinterpret_cast<float4*>(io + (size_t)r * DD + li * 4) = sup;
    }
}

// ---------------------------------------------------------------------------
// Kernel 3: in-place linear+blend on io (round-2-proven shape, no spills).
//   out = theta*(support @ W.T + b) + (1-theta)*support
// 64-row tile, 512 threads, launch_bounds(512,4) -> 128 VGPR budget.
// support fp32 in LDS (epilogue re-reads LDS, no live-across-loop regs);
// W^T bf16 in LDS, ds_read_b128 weight loads. LDS 68.6KB -> 2 blocks/CU.
// ---------------------------------------------------------------------------
#define RPB 64
#define SPAD 132    // fp32 pad: 528B rows, 16B-aligned, conflict-spread
#define WPAD 136    // bf16 pad: 272B rows = 17*16B

__device__ __forceinline__ float bf16lo(unsigned u) {
    return __uint_as_float(u << 16);
}
__device__ __forceinline__ float bf16hi(unsigned u) {
    return __uint_as_float(u & 0xffff0000u);
}

__global__ __launch_bounds__(512, 4) void lin_kernel(
    float* io, const float* __restrict__ W, const float* __restrict__ b,
    const int* __restrict__ lptr)
{
    __shared__ float sS[RPB][SPAD];            // support fp32 (33.8 KB)
    __shared__ __hip_bfloat16 sWt[DD][WPAD];   // W^T bf16 (34.8 KB)

    const int tid = threadIdx.x;
    const int r0  = blockIdx.x * RPB;
    const int tr  = tid >> 4;   // 0..31 -> rows tr*2..+1
    const int tc  = tid & 15;   // 0..15 -> cols tc*8..+7

    const int lv = *lptr;
    const float theta  = logf(BETA / (float)lv + 1.0f);
    const float mtheta = 1.0f - theta;

    // --- stage W transposed (bf16) ---
    for (int i = tid * 4; i < DD * DD; i += 512 * 4) {
        const float4 w4 = *reinterpret_cast<const float4*>(W + i);
        const int o = i >> 7;
        const int k = i & 127;
        sWt[k + 0][o] = __float2bfloat16(w4.x);
        sWt[k + 1][o] = __float2bfloat16(w4.y);
        sWt[k + 2][o] = __float2bfloat16(w4.z);
        sWt[k + 3][o] = __float2bfloat16(w4.w);
    }

    // --- stage support tile fp32 (coalesced float4 copy) ---
    for (int idx = tid; idx < RPB * 32; idx += 512) {
        const int row = idx >> 5;
        const int q   = idx & 31;
        const int rr  = r0 + row;
        const float4 v = (rr < NN)
            ? *reinterpret_cast<const float4*>(io + (size_t)rr * DD + q * 4)
            : make_float4(0.f, 0.f, 0.f, 0.f);
        *reinterpret_cast<float4*>(&sS[row][q * 4]) = v;
    }
    __syncthreads();

    // --- GEMM: 2 rows x 8 cols per thread, fp32 A, bf16 W, fp32 accum ---
    float acc[2][8];
    #pragma unroll
    for (int i = 0; i < 2; ++i)
        #pragma unroll
        for (int j = 0; j < 8; ++j) acc[i][j] = 0.f;

    for (int k = 0; k < DD; k += 4) {
        const float4 a0 = *reinterpret_cast<const float4*>(&sS[tr * 2 + 0][k]);
        const float4 a1 = *reinterpret_cast<const float4*>(&sS[tr * 2 + 1][k]);
        const float aa0[4] = {a0.x, a0.y, a0.z, a0.w};
        const float aa1[4] = {a1.x, a1.y, a1.z, a1.w};
        #pragma unroll
        for (int kk = 0; kk < 4; ++kk) {
            const uint4 wr = *reinterpret_cast<const uint4*>(&sWt[k + kk][tc * 8]);
            float w[8];
            w[0] = bf16lo(wr.x); w[1] = bf16hi(wr.x);
            w[2] = bf16lo(wr.y); w[3] = bf16hi(wr.y);
            w[4] = bf16lo(wr.z); w[5] = bf16hi(wr.z);
            w[6] = bf16lo(wr.w); w[7] = bf16hi(wr.w);
            #pragma unroll
            for (int j = 0; j < 8; ++j) {
                acc[0][j] = fmaf(aa0[kk], w[j], acc[0][j]);
                acc[1][j] = fmaf(aa1[kk], w[j], acc[1][j]);
            }
        }
    }

    // --- epilogue: blend with fp32 support re-read from LDS, write in place ---
    #pragma unroll
    for (int i = 0; i < 2; ++i) {
        const int ri = tr * 2 + i;
        const int rr = r0 + ri;
        if (rr >= NN) continue;
        #pragma unroll
        for (int j4 = 0; j4 < 2; ++j4) {
            const int cc = tc * 8 + j4 * 4;
            const float4 bv  = *reinterpret_cast<const float4*>(&b[cc]);
            const float4 sup = *reinterpret_cast<const float4*>(&sS[ri][cc]);
            float4 o4;
            o4.x = theta * (acc[i][j4 * 4 + 0] + bv.x) + mtheta * sup.x;
            o4.y = theta * (acc[i][j4 * 4 + 1] + bv.y) + mtheta * sup.y;
            o4.z = theta * (acc[i][j4 * 4 + 2] + bv.z) + mtheta * sup.z;
            o4.w = theta * (acc[i][j4 * 4 + 3] + bv.w) + mtheta * sup.w;
            *reinterpret_cast<float4*>(io + (size_t)rr * DD + cc) = o4;
        }
    }
}

extern "C" void kernel_launch(void* const* d_in, const int* in_sizes, int n_in,
                              void* d_out, int out_size, void* d_ws, size_t ws_size,
                              hipStream_t stream) {
    const float* h         = (const float*)d_in[0];
    const float* h0        = (const float*)d_in[1];
    const int*   edge_row  = (const int*)d_in[2];
    const int*   edge_col  = (const int*)d_in[3];
    const float* edge_vals = (const float*)d_in[4];
    const float* W         = (const float*)d_in[5];
    const float* b         = (const float*)d_in[6];
    const int*   lptr      = (const int*)d_in[7];
    const int E = in_sizes[2];

    int* rp = (int*)d_ws;  // N+1 ints (~200KB)
    float* io = (float*)d_out;

    build_rowptr<<<(E + 1 + 255) / 256, 256, 0, stream>>>(edge_row, E, rp);

    agg_kernel<<<(NN + 3) / 4, 256, 0, stream>>>(h, h0, edge_col, edge_vals, rp, io);

    lin_kernel<<<(NN + RPB - 1) / RPB, 512, 0, stream>>>(io, W, b, lptr);
}

// Round 5
// 96.604 us; speedup vs baseline: 2.1466x; 1.2086x over previous
//
#include <hip/hip_runtime.h>
#include <hip/hip_bf16.h>
#include <math.h>

#define NN 50000
#define DD 128
#define ALPHA 0.1f
#define BETA 0.5f

// ---------------------------------------------------------------------------
// Kernel 1: prep = build CSR row pointer + (optionally) convert h to bf16.
// hb == nullptr -> rowptr only.
// ---------------------------------------------------------------------------
__global__ __launch_bounds__(256) void prep_kernel(
    const int* __restrict__ edge_row, int E, int* __restrict__ rp,
    const float* __restrict__ h, ushort* __restrict__ hb)
{
    const int t = blockIdx.x * 256 + threadIdx.x;

    if (hb != nullptr && t < NN * DD / 4) {
        const float4 v = *reinterpret_cast<const float4*>(h + (size_t)t * 4);
        ushort4 o;
        o.x = __bfloat16_as_ushort(__float2bfloat16(v.x));
        o.y = __bfloat16_as_ushort(__float2bfloat16(v.y));
        o.z = __bfloat16_as_ushort(__float2bfloat16(v.z));
        o.w = __bfloat16_as_ushort(__float2bfloat16(v.w));
        *reinterpret_cast<ushort4*>(hb + (size_t)t * 4) = o;
    }

    if (t <= E) {
        if (t == 0) {
            int r0 = edge_row[0];
            for (int r = 0; r <= r0; ++r) rp[r] = 0;
        } else if (t == E) {
            int rl = edge_row[E - 1];
            for (int r = rl + 1; r <= NN; ++r) rp[r] = E;
        } else {
            int rprev = edge_row[t - 1];
            int rcur  = edge_row[t];
            for (int r = rprev + 1; r <= rcur; ++r) rp[r] = t;
        }
    }
}

__device__ __forceinline__ float bf16lo(unsigned u) {
    return __uint_as_float(u << 16);
}
__device__ __forceinline__ float bf16hi(unsigned u) {
    return __uint_as_float(u & 0xffff0000u);
}

// ---------------------------------------------------------------------------
// Kernel 2a: bf16-gather aggregation. One wave per row, no LDS.
//   io[r] = 0.9 * sum_e val[e]*hb[col[e]] + 0.1 * h0[r]
// g = lane>>4 (edge slot), li = lane&15 (features li*8..+7 as uint4/8bf16).
// 4-way unroll -> 16 edges / 4 independent gathers in flight.
// ---------------------------------------------------------------------------
__global__ __launch_bounds__(256, 8) void agg_bf16(
    const ushort* __restrict__ hb, const float* __restrict__ h0,
    const int* __restrict__ edge_col, const float* __restrict__ edge_vals,
    const int* __restrict__ rp, float* __restrict__ io)
{
    const int wave = threadIdx.x >> 6;
    const int lane = threadIdx.x & 63;
    const int g    = lane >> 4;
    const int li   = lane & 15;
    const int r    = blockIdx.x * 4 + wave;
    if (r >= NN) return;

    const int e0 = rp[r], e1 = rp[r + 1];

    float acc[8];
    #pragma unroll
    for (int j = 0; j < 8; ++j) acc[j] = 0.f;

    for (int eb = e0; eb < e1; eb += 16) {
        #pragma unroll
        for (int u = 0; u < 4; ++u) {
            const int e  = eb + u * 4 + g;
            const int ee = min(e, e1 - 1);
            const int   c = edge_col[ee];
            const float v = (e < e1) ? edge_vals[ee] : 0.0f;
            const uint4 hv = *reinterpret_cast<const uint4*>(
                hb + (size_t)c * DD + li * 8);
            acc[0] = fmaf(v, bf16lo(hv.x), acc[0]);
            acc[1] = fmaf(v, bf16hi(hv.x), acc[1]);
            acc[2] = fmaf(v, bf16lo(hv.y), acc[2]);
            acc[3] = fmaf(v, bf16hi(hv.y), acc[3]);
            acc[4] = fmaf(v, bf16lo(hv.z), acc[4]);
            acc[5] = fmaf(v, bf16hi(hv.z), acc[5]);
            acc[6] = fmaf(v, bf16lo(hv.w), acc[6]);
            acc[7] = fmaf(v, bf16hi(hv.w), acc[7]);
        }
    }

    #pragma unroll
    for (int j = 0; j < 8; ++j) {
        acc[j] += __shfl_xor(acc[j], 16);
        acc[j] += __shfl_xor(acc[j], 32);
    }

    if (g == 0) {
        const float4 h0a = *reinterpret_cast<const float4*>(
            h0 + (size_t)r * DD + li * 8);
        const float4 h0b = *reinterpret_cast<const float4*>(
            h0 + (size_t)r * DD + li * 8 + 4);
        float4 oa, ob;
        oa.x = fmaf(1.0f - ALPHA, acc[0], ALPHA * h0a.x);
        oa.y = fmaf(1.0f - ALPHA, acc[1], ALPHA * h0a.y);
        oa.z = fmaf(1.0f - ALPHA, acc[2], ALPHA * h0a.z);
        oa.w = fmaf(1.0f - ALPHA, acc[3], ALPHA * h0a.w);
        ob.x = fmaf(1.0f - ALPHA, acc[4], ALPHA * h0b.x);
        ob.y = fmaf(1.0f - ALPHA, acc[5], ALPHA * h0b.y);
        ob.z = fmaf(1.0f - ALPHA, acc[6], ALPHA * h0b.z);
        ob.w = fmaf(1.0f - ALPHA, acc[7], ALPHA * h0b.w);
        *reinterpret_cast<float4*>(io + (size_t)r * DD + li * 8)     = oa;
        *reinterpret_cast<float4*>(io + (size_t)r * DD + li * 8 + 4) = ob;
    }
}

// ---------------------------------------------------------------------------
// Kernel 2b: fp32 fallback aggregation (ws too small for bf16 table).
// ---------------------------------------------------------------------------
__global__ __launch_bounds__(256, 6) void agg_fp32(
    const float* __restrict__ h, const float* __restrict__ h0,
    const int* __restrict__ edge_col, const float* __restrict__ edge_vals,
    const int* __restrict__ rp, float* __restrict__ io)
{
    const int wave = threadIdx.x >> 6;
    const int lane = threadIdx.x & 63;
    const int p    = lane >> 5;
    const int li   = lane & 31;
    const int r    = blockIdx.x * 4 + wave;
    if (r >= NN) return;

    const int e0 = rp[r], e1 = rp[r + 1];

    float4 A[4];
    #pragma unroll
    for (int u = 0; u < 4; ++u) A[u] = make_float4(0.f, 0.f, 0.f, 0.f);

    for (int eb = e0; eb < e1; eb += 8) {
        #pragma unroll
        for (int u = 0; u < 4; ++u) {
            const int e  = eb + 2 * u + p;
            const int ee = min(e, e1 - 1);
            const int   c = edge_col[ee];
            const float v = (e < e1) ? edge_vals[ee] : 0.0f;
            const float4 hv =
                *reinterpret_cast<const float4*>(h + (size_t)c * DD + li * 4);
            A[u].x = fmaf(v, hv.x, A[u].x);
            A[u].y = fmaf(v, hv.y, A[u].y);
            A[u].z = fmaf(v, hv.z, A[u].z);
            A[u].w = fmaf(v, hv.w, A[u].w);
        }
    }
    float4 s;
    s.x = (A[0].x + A[1].x) + (A[2].x + A[3].x);
    s.y = (A[0].y + A[1].y) + (A[2].y + A[3].y);
    s.z = (A[0].z + A[1].z) + (A[2].z + A[3].z);
    s.w = (A[0].w + A[1].w) + (A[2].w + A[3].w);
    s.x += __shfl_xor(s.x, 32);
    s.y += __shfl_xor(s.y, 32);
    s.z += __shfl_xor(s.z, 32);
    s.w += __shfl_xor(s.w, 32);

    if (p == 0) {
        const float4 h0v =
            *reinterpret_cast<const float4*>(h0 + (size_t)r * DD + li * 4);
        float4 sup;
        sup.x = fmaf(1.0f - ALPHA, s.x, ALPHA * h0v.x);
        sup.y = fmaf(1.0f - ALPHA, s.y, ALPHA * h0v.y);
        sup.z = fmaf(1.0f - ALPHA, s.z, ALPHA * h0v.z);
        sup.w = fmaf(1.0f - ALPHA, s.w, ALPHA * h0v.w);
        *reinterpret_cast<float4*>(io + (size_t)r * DD + li * 4) = sup;
    }
}

// ---------------------------------------------------------------------------
// Kernel 3: in-place linear+blend on io (round-4-proven, unchanged).
// ---------------------------------------------------------------------------
#define RPB 64
#define SPAD 132
#define WPAD 136

__global__ __launch_bounds__(512, 4) void lin_kernel(
    float* io, const float* __restrict__ W, const float* __restrict__ b,
    const int* __restrict__ lptr)
{
    __shared__ float sS[RPB][SPAD];
    __shared__ __hip_bfloat16 sWt[DD][WPAD];

    const int tid = threadIdx.x;
    const int r0  = blockIdx.x * RPB;
    const int tr  = tid >> 4;
    const int tc  = tid & 15;

    const int lv = *lptr;
    const float theta  = logf(BETA / (float)lv + 1.0f);
    const float mtheta = 1.0f - theta;

    for (int i = tid * 4; i < DD * DD; i += 512 * 4) {
        const float4 w4 = *reinterpret_cast<const float4*>(W + i);
        const int o = i >> 7;
        const int k = i & 127;
        sWt[k + 0][o] = __float2bfloat16(w4.x);
        sWt[k + 1][o] = __float2bfloat16(w4.y);
        sWt[k + 2][o] = __float2bfloat16(w4.z);
        sWt[k + 3][o] = __float2bfloat16(w4.w);
    }

    for (int idx = tid; idx < RPB * 32; idx += 512) {
        const int row = idx >> 5;
        const int q   = idx & 31;
        const int rr  = r0 + row;
        const float4 v = (rr < NN)
            ? *reinterpret_cast<const float4*>(io + (size_t)rr * DD + q * 4)
            : make_float4(0.f, 0.f, 0.f, 0.f);
        *reinterpret_cast<float4*>(&sS[row][q * 4]) = v;
    }
    __syncthreads();

    float acc[2][8];
    #pragma unroll
    for (int i = 0; i < 2; ++i)
        #pragma unroll
        for (int j = 0; j < 8; ++j) acc[i][j] = 0.f;

    for (int k = 0; k < DD; k += 4) {
        const float4 a0 = *reinterpret_cast<const float4*>(&sS[tr * 2 + 0][k]);
        const float4 a1 = *reinterpret_cast<const float4*>(&sS[tr * 2 + 1][k]);
        const float aa0[4] = {a0.x, a0.y, a0.z, a0.w};
        const float aa1[4] = {a1.x, a1.y, a1.z, a1.w};
        #pragma unroll
        for (int kk = 0; kk < 4; ++kk) {
            const uint4 wr = *reinterpret_cast<const uint4*>(&sWt[k + kk][tc * 8]);
            float w[8];
            w[0] = bf16lo(wr.x); w[1] = bf16hi(wr.x);
            w[2] = bf16lo(wr.y); w[3] = bf16hi(wr.y);
            w[4] = bf16lo(wr.z); w[5] = bf16hi(wr.z);
            w[6] = bf16lo(wr.w); w[7] = bf16hi(wr.w);
            #pragma unroll
            for (int j = 0; j < 8; ++j) {
                acc[0][j] = fmaf(aa0[kk], w[j], acc[0][j]);
                acc[1][j] = fmaf(aa1[kk], w[j], acc[1][j]);
            }
        }
    }

    #pragma unroll
    for (int i = 0; i < 2; ++i) {
        const int ri = tr * 2 + i;
        const int rr = r0 + ri;
        if (rr >= NN) continue;
        #pragma unroll
        for (int j4 = 0; j4 < 2; ++j4) {
            const int cc = tc * 8 + j4 * 4;
            const float4 bv  = *reinterpret_cast<const float4*>(&b[cc]);
            const float4 sup = *reinterpret_cast<const float4*>(&sS[ri][cc]);
            float4 o4;
            o4.x = theta * (acc[i][j4 * 4 + 0] + bv.x) + mtheta * sup.x;
            o4.y = theta * (acc[i][j4 * 4 + 1] + bv.y) + mtheta * sup.y;
            o4.z = theta * (acc[i][j4 * 4 + 2] + bv.z) + mtheta * sup.z;
            o4.w = theta * (acc[i][j4 * 4 + 3] + bv.w) + mtheta * sup.w;
            *reinterpret_cast<float4*>(io + (size_t)rr * DD + cc) = o4;
        }
    }
}

extern "C" void kernel_launch(void* const* d_in, const int* in_sizes, int n_in,
                              void* d_out, int out_size, void* d_ws, size_t ws_size,
                              hipStream_t stream) {
    const float* h         = (const float*)d_in[0];
    const float* h0        = (const float*)d_in[1];
    const int*   edge_row  = (const int*)d_in[2];
    const int*   edge_col  = (const int*)d_in[3];
    const float* edge_vals = (const float*)d_in[4];
    const float* W         = (const float*)d_in[5];
    const float* b         = (const float*)d_in[6];
    const int*   lptr      = (const int*)d_in[7];
    const int E = in_sizes[2];

    int*    rp = (int*)d_ws;                          // N+1 ints (~200KB)
    ushort* hb = (ushort*)((char*)d_ws + (1 << 18));  // bf16 h table (12.8MB)
    float*  io = (float*)d_out;

    const size_t need = (size_t)(1 << 18) + (size_t)NN * DD * sizeof(ushort);
    const bool use_bf16 = (ws_size >= need);

    const int convT = NN * DD / 4;  // 1.6M conversion threads (> E+1)
    const int gridP = (convT + 255) / 256;
    prep_kernel<<<gridP, 256, 0, stream>>>(edge_row, E, rp, h,
                                           use_bf16 ? hb : nullptr);

    if (use_bf16) {
        agg_bf16<<<(NN + 3) / 4, 256, 0, stream>>>(hb, h0, edge_col, edge_vals, rp, io);
    } else {
        agg_fp32<<<(NN + 3) / 4, 256, 0, stream>>>(h, h0, edge_col, edge_vals, rp, io);
    }

    lin_kernel<<<(NN + RPB - 1) / RPB, 512, 0, stream>>>(io, W, b, lptr);
}

// Round 6
// 79.571 us; speedup vs baseline: 2.6061x; 1.2141x over previous
//
#include <hip/hip_runtime.h>
#include <hip/hip_bf16.h>
#include <math.h>

#define NN 50000
#define DD 128
#define ALPHA 0.1f
#define BETA 0.5f

typedef __attribute__((ext_vector_type(8))) short short8;   // bf16x8 MFMA frag
typedef __attribute__((ext_vector_type(4))) float floatx4;  // f32x4 accum

__device__ __forceinline__ float bf16lo(unsigned u) {
    return __uint_as_float(u << 16);
}
__device__ __forceinline__ float bf16hi(unsigned u) {
    return __uint_as_float(u & 0xffff0000u);
}
__device__ __forceinline__ unsigned pkbf(float a, float b) {
    unsigned la = (unsigned)__bfloat16_as_ushort(__float2bfloat16(a));
    unsigned lb = (unsigned)__bfloat16_as_ushort(__float2bfloat16(b));
    return la | (lb << 16);
}

// ---------------------------------------------------------------------------
// Kernel 1: prep = rowptr + h->bf16 + W->bf16 (all fused, one launch).
// ---------------------------------------------------------------------------
__global__ __launch_bounds__(256) void prep_kernel(
    const int* __restrict__ edge_row, int E, int* __restrict__ rp,
    const float* __restrict__ h, ushort* __restrict__ hb,
    const float* __restrict__ W, ushort* __restrict__ wb)
{
    const int t = blockIdx.x * 256 + threadIdx.x;

    if (hb != nullptr && t < NN * DD / 4) {
        const float4 v = *reinterpret_cast<const float4*>(h + (size_t)t * 4);
        ushort4 o;
        o.x = __bfloat16_as_ushort(__float2bfloat16(v.x));
        o.y = __bfloat16_as_ushort(__float2bfloat16(v.y));
        o.z = __bfloat16_as_ushort(__float2bfloat16(v.z));
        o.w = __bfloat16_as_ushort(__float2bfloat16(v.w));
        *reinterpret_cast<ushort4*>(hb + (size_t)t * 4) = o;
    }

    if (wb != nullptr && t < DD * DD / 4) {
        const float4 v = *reinterpret_cast<const float4*>(W + (size_t)t * 4);
        ushort4 o;
        o.x = __bfloat16_as_ushort(__float2bfloat16(v.x));
        o.y = __bfloat16_as_ushort(__float2bfloat16(v.y));
        o.z = __bfloat16_as_ushort(__float2bfloat16(v.z));
        o.w = __bfloat16_as_ushort(__float2bfloat16(v.w));
        *reinterpret_cast<ushort4*>(wb + (size_t)t * 4) = o;
    }

    if (t <= E) {
        if (t == 0) {
            int r0 = edge_row[0];
            for (int r = 0; r <= r0; ++r) rp[r] = 0;
        } else if (t == E) {
            int rl = edge_row[E - 1];
            for (int r = rl + 1; r <= NN; ++r) rp[r] = E;
        } else {
            int rprev = edge_row[t - 1];
            int rcur  = edge_row[t];
            for (int r = rprev + 1; r <= rcur; ++r) rp[r] = t;
        }
    }
}

// ---------------------------------------------------------------------------
// Kernel 2a: bf16-gather aggregation (round-5-proven, unchanged).
// ---------------------------------------------------------------------------
__global__ __launch_bounds__(256, 8) void agg_bf16(
    const ushort* __restrict__ hb, const float* __restrict__ h0,
    const int* __restrict__ edge_col, const float* __restrict__ edge_vals,
    const int* __restrict__ rp, float* __restrict__ io)
{
    const int wave = threadIdx.x >> 6;
    const int lane = threadIdx.x & 63;
    const int g    = lane >> 4;
    const int li   = lane & 15;
    const int r    = blockIdx.x * 4 + wave;
    if (r >= NN) return;

    const int e0 = rp[r], e1 = rp[r + 1];

    float acc[8];
    #pragma unroll
    for (int j = 0; j < 8; ++j) acc[j] = 0.f;

    for (int eb = e0; eb < e1; eb += 16) {
        #pragma unroll
        for (int u = 0; u < 4; ++u) {
            const int e  = eb + u * 4 + g;
            const int ee = min(e, e1 - 1);
            const int   c = edge_col[ee];
            const float v = (e < e1) ? edge_vals[ee] : 0.0f;
            const uint4 hv = *reinterpret_cast<const uint4*>(
                hb + (size_t)c * DD + li * 8);
            acc[0] = fmaf(v, bf16lo(hv.x), acc[0]);
            acc[1] = fmaf(v, bf16hi(hv.x), acc[1]);
            acc[2] = fmaf(v, bf16lo(hv.y), acc[2]);
            acc[3] = fmaf(v, bf16hi(hv.y), acc[3]);
            acc[4] = fmaf(v, bf16lo(hv.z), acc[4]);
            acc[5] = fmaf(v, bf16hi(hv.z), acc[5]);
            acc[6] = fmaf(v, bf16lo(hv.w), acc[6]);
            acc[7] = fmaf(v, bf16hi(hv.w), acc[7]);
        }
    }

    #pragma unroll
    for (int j = 0; j < 8; ++j) {
        acc[j] += __shfl_xor(acc[j], 16);
        acc[j] += __shfl_xor(acc[j], 32);
    }

    if (g == 0) {
        const float4 h0a = *reinterpret_cast<const float4*>(
            h0 + (size_t)r * DD + li * 8);
        const float4 h0b = *reinterpret_cast<const float4*>(
            h0 + (size_t)r * DD + li * 8 + 4);
        float4 oa, ob;
        oa.x = fmaf(1.0f - ALPHA, acc[0], ALPHA * h0a.x);
        oa.y = fmaf(1.0f - ALPHA, acc[1], ALPHA * h0a.y);
        oa.z = fmaf(1.0f - ALPHA, acc[2], ALPHA * h0a.z);
        oa.w = fmaf(1.0f - ALPHA, acc[3], ALPHA * h0a.w);
        ob.x = fmaf(1.0f - ALPHA, acc[4], ALPHA * h0b.x);
        ob.y = fmaf(1.0f - ALPHA, acc[5], ALPHA * h0b.y);
        ob.z = fmaf(1.0f - ALPHA, acc[6], ALPHA * h0b.z);
        ob.w = fmaf(1.0f - ALPHA, acc[7], ALPHA * h0b.w);
        *reinterpret_cast<float4*>(io + (size_t)r * DD + li * 8)     = oa;
        *reinterpret_cast<float4*>(io + (size_t)r * DD + li * 8 + 4) = ob;
    }
}

// ---------------------------------------------------------------------------
// Kernel 2b: fp32 fallback aggregation (ws too small for bf16 tables).
// ---------------------------------------------------------------------------
__global__ __launch_bounds__(256, 6) void agg_fp32(
    const float* __restrict__ h, const float* __restrict__ h0,
    const int* __restrict__ edge_col, const float* __restrict__ edge_vals,
    const int* __restrict__ rp, float* __restrict__ io)
{
    const int wave = threadIdx.x >> 6;
    const int lane = threadIdx.x & 63;
    const int p    = lane >> 5;
    const int li   = lane & 31;
    const int r    = blockIdx.x * 4 + wave;
    if (r >= NN) return;

    const int e0 = rp[r], e1 = rp[r + 1];

    float4 A[4];
    #pragma unroll
    for (int u = 0; u < 4; ++u) A[u] = make_float4(0.f, 0.f, 0.f, 0.f);

    for (int eb = e0; eb < e1; eb += 8) {
        #pragma unroll
        for (int u = 0; u < 4; ++u) {
            const int e  = eb + 2 * u + p;
            const int ee = min(e, e1 - 1);
            const int   c = edge_col[ee];
            const float v = (e < e1) ? edge_vals[ee] : 0.0f;
            const float4 hv =
                *reinterpret_cast<const float4*>(h + (size_t)c * DD + li * 4);
            A[u].x = fmaf(v, hv.x, A[u].x);
            A[u].y = fmaf(v, hv.y, A[u].y);
            A[u].z = fmaf(v, hv.z, A[u].z);
            A[u].w = fmaf(v, hv.w, A[u].w);
        }
    }
    float4 s;
    s.x = (A[0].x + A[1].x) + (A[2].x + A[3].x);
    s.y = (A[0].y + A[1].y) + (A[2].y + A[3].y);
    s.z = (A[0].z + A[1].z) + (A[2].z + A[3].z);
    s.w = (A[0].w + A[1].w) + (A[2].w + A[3].w);
    s.x += __shfl_xor(s.x, 32);
    s.y += __shfl_xor(s.y, 32);
    s.z += __shfl_xor(s.z, 32);
    s.w += __shfl_xor(s.w, 32);

    if (p == 0) {
        const float4 h0v =
            *reinterpret_cast<const float4*>(h0 + (size_t)r * DD + li * 4);
        float4 sup;
        sup.x = fmaf(1.0f - ALPHA, s.x, ALPHA * h0v.x);
        sup.y = fmaf(1.0f - ALPHA, s.y, ALPHA * h0v.y);
        sup.z = fmaf(1.0f - ALPHA, s.z, ALPHA * h0v.z);
        sup.w = fmaf(1.0f - ALPHA, s.w, ALPHA * h0v.w);
        *reinterpret_cast<float4*>(io + (size_t)r * DD + li * 4) = sup;
    }
}

// ---------------------------------------------------------------------------
// Kernel 3a: MFMA linear+blend (in place on io).
//   out = theta*(sup @ W^T + b) + (1-theta)*sup
// 64 rows/block, 256 threads (4 waves). Wave w owns rows [w*16, w*16+16).
// A-frag: sA bf16 LDS row-major; lane layout row=lane&15, k=(lane>>4)*8+i.
// B-frag: wb (bf16 W, row-major [out][in]) straight from global (L2-hot);
//         col=lane&15, k contiguous -> one 16B load, no transpose needed.
// C-layout (verified): col=lane&15, row=(lane>>4)*4+reg.
// LDS: sS fp32 [64][132] 33.8KB + sA bf16 [64][136] 17.4KB = 51.2KB -> 3/CU.
// ---------------------------------------------------------------------------
__global__ __launch_bounds__(256, 3) void lin_mfma(
    float* io, const ushort* __restrict__ wb, const float* __restrict__ b,
    const int* __restrict__ lptr)
{
    __shared__ float  sS[64][132];
    __shared__ ushort sA[64][136];

    const int tid = threadIdx.x;
    const int r0  = blockIdx.x * 64;

    const int lv = *lptr;
    const float theta  = logf(BETA / (float)lv + 1.0f);
    const float mtheta = 1.0f - theta;

    // --- stage: fp32 -> sS, packed bf16 -> sA (8 floats per iter/thread) ---
    for (int idx = tid; idx < 64 * 16; idx += 256) {
        const int row = idx >> 4;
        const int c8  = (idx & 15) * 8;
        const int rr  = r0 + row;
        float4 v0 = make_float4(0.f, 0.f, 0.f, 0.f);
        float4 v1 = make_float4(0.f, 0.f, 0.f, 0.f);
        if (rr < NN) {
            v0 = *reinterpret_cast<const float4*>(io + (size_t)rr * DD + c8);
            v1 = *reinterpret_cast<const float4*>(io + (size_t)rr * DD + c8 + 4);
        }
        *reinterpret_cast<float4*>(&sS[row][c8])     = v0;
        *reinterpret_cast<float4*>(&sS[row][c8 + 4]) = v1;
        uint4 pk;
        pk.x = pkbf(v0.x, v0.y);
        pk.y = pkbf(v0.z, v0.w);
        pk.z = pkbf(v1.x, v1.y);
        pk.w = pkbf(v1.z, v1.w);
        *reinterpret_cast<uint4*>(&sA[row][c8]) = pk;
    }
    __syncthreads();

    const int wave = tid >> 6;
    const int lane = tid & 63;
    const int m0   = wave * 16;              // M-tile base row (in block)
    const int la   = lane & 15;
    const int k0   = (lane >> 4) * 8;

    floatx4 acc[8];
    #pragma unroll
    for (int t = 0; t < 8; ++t) acc[t] = (floatx4){0.f, 0.f, 0.f, 0.f};

    #pragma unroll
    for (int s = 0; s < 4; ++s) {
        const int k = s * 32 + k0;
        const short8 af = *reinterpret_cast<const short8*>(&sA[m0 + la][k]);
        #pragma unroll
        for (int t = 0; t < 8; ++t) {
            const int col = t * 16 + la;
            const short8 bf = *reinterpret_cast<const short8*>(
                wb + (size_t)col * DD + k);
            acc[t] = __builtin_amdgcn_mfma_f32_16x16x32_bf16(af, bf, acc[t], 0, 0, 0);
        }
    }

    // --- epilogue: blend + scalar stores per C-layout ---
    const int rg = (lane >> 4) * 4;
    #pragma unroll
    for (int t = 0; t < 8; ++t) {
        const int c  = t * 16 + la;
        const float bb = b[c];
        #pragma unroll
        for (int j = 0; j < 4; ++j) {
            const int rl = m0 + rg + j;
            const int rr = r0 + rl;
            if (rr < NN) {
                const float sup = sS[rl][c];
                io[(size_t)rr * DD + c] =
                    theta * (acc[t][j] + bb) + mtheta * sup;
            }
        }
    }
}

// ---------------------------------------------------------------------------
// Kernel 3b: fallback fp32-vector linear+blend (round-4-proven).
// ---------------------------------------------------------------------------
#define RPB 64
#define SPAD 132
#define WPAD 136

__global__ __launch_bounds__(512, 4) void lin_kernel(
    float* io, const float* __restrict__ W, const float* __restrict__ b,
    const int* __restrict__ lptr)
{
    __shared__ float sS[RPB][SPAD];
    __shared__ __hip_bfloat16 sWt[DD][WPAD];

    const int tid = threadIdx.x;
    const int r0  = blockIdx.x * RPB;
    const int tr  = tid >> 4;
    const int tc  = tid & 15;

    const int lv = *lptr;
    const float theta  = logf(BETA / (float)lv + 1.0f);
    const float mtheta = 1.0f - theta;

    for (int i = tid * 4; i < DD * DD; i += 512 * 4) {
        const float4 w4 = *reinterpret_cast<const float4*>(W + i);
        const int o = i >> 7;
        const int k = i & 127;
        sWt[k + 0][o] = __float2bfloat16(w4.x);
        sWt[k + 1][o] = __float2bfloat16(w4.y);
        sWt[k + 2][o] = __float2bfloat16(w4.z);
        sWt[k + 3][o] = __float2bfloat16(w4.w);
    }

    for (int idx = tid; idx < RPB * 32; idx += 512) {
        const int row = idx >> 5;
        const int q   = idx & 31;
        const int rr  = r0 + row;
        const float4 v = (rr < NN)
            ? *reinterpret_cast<const float4*>(io + (size_t)rr * DD + q * 4)
            : make_float4(0.f, 0.f, 0.f, 0.f);
        *reinterpret_cast<float4*>(&sS[row][q * 4]) = v;
    }
    __syncthreads();

    float acc[2][8];
    #pragma unroll
    for (int i = 0; i < 2; ++i)
        #pragma unroll
        for (int j = 0; j < 8; ++j) acc[i][j] = 0.f;

    for (int k = 0; k < DD; k += 4) {
        const float4 a0 = *reinterpret_cast<const float4*>(&sS[tr * 2 + 0][k]);
        const float4 a1 = *reinterpret_cast<const float4*>(&sS[tr * 2 + 1][k]);
        const float aa0[4] = {a0.x, a0.y, a0.z, a0.w};
        const float aa1[4] = {a1.x, a1.y, a1.z, a1.w};
        #pragma unroll
        for (int kk = 0; kk < 4; ++kk) {
            const uint4 wr = *reinterpret_cast<const uint4*>(&sWt[k + kk][tc * 8]);
            float w[8];
            w[0] = bf16lo(wr.x); w[1] = bf16hi(wr.x);
            w[2] = bf16lo(wr.y); w[3] = bf16hi(wr.y);
            w[4] = bf16lo(wr.z); w[5] = bf16hi(wr.z);
            w[6] = bf16lo(wr.w); w[7] = bf16hi(wr.w);
            #pragma unroll
            for (int j = 0; j < 8; ++j) {
                acc[0][j] = fmaf(aa0[kk], w[j], acc[0][j]);
                acc[1][j] = fmaf(aa1[kk], w[j], acc[1][j]);
            }
        }
    }

    #pragma unroll
    for (int i = 0; i < 2; ++i) {
        const int ri = tr * 2 + i;
        const int rr = r0 + ri;
        if (rr >= NN) continue;
        #pragma unroll
        for (int j4 = 0; j4 < 2; ++j4) {
            const int cc = tc * 8 + j4 * 4;
            const float4 bv  = *reinterpret_cast<const float4*>(&b[cc]);
            const float4 sup = *reinterpret_cast<const float4*>(&sS[ri][cc]);
            float4 o4;
            o4.x = theta * (acc[i][j4 * 4 + 0] + bv.x) + mtheta * sup.x;
            o4.y = theta * (acc[i][j4 * 4 + 1] + bv.y) + mtheta * sup.y;
            o4.z = theta * (acc[i][j4 * 4 + 2] + bv.z) + mtheta * sup.z;
            o4.w = theta * (acc[i][j4 * 4 + 3] + bv.w) + mtheta * sup.w;
            *reinterpret_cast<float4*>(io + (size_t)rr * DD + cc) = o4;
        }
    }
}

extern "C" void kernel_launch(void* const* d_in, const int* in_sizes, int n_in,
                              void* d_out, int out_size, void* d_ws, size_t ws_size,
                              hipStream_t stream) {
    const float* h         = (const float*)d_in[0];
    const float* h0        = (const float*)d_in[1];
    const int*   edge_row  = (const int*)d_in[2];
    const int*   edge_col  = (const int*)d_in[3];
    const float* edge_vals = (const float*)d_in[4];
    const float* W         = (const float*)d_in[5];
    const float* b         = (const float*)d_in[6];
    const int*   lptr      = (const int*)d_in[7];
    const int E = in_sizes[2];

    // ws layout: rp (256KB) | hb bf16 h (12.8MB) | wb bf16 W (32KB)
    char* wsb = (char*)d_ws;
    int*    rp = (int*)wsb;
    ushort* hb = (ushort*)(wsb + (1 << 18));
    ushort* wb = (ushort*)(wsb + (1 << 18) + (size_t)NN * DD * sizeof(ushort));
    float*  io = (float*)d_out;

    const size_t need = (size_t)(1 << 18)
                      + (size_t)NN * DD * sizeof(ushort)
                      + (size_t)DD * DD * sizeof(ushort);
    const bool fast = (ws_size >= need);

    const int convT = NN * DD / 4;  // 1.6M threads (covers E+1 and W conv)
    const int gridP = (convT + 255) / 256;
    prep_kernel<<<gridP, 256, 0, stream>>>(edge_row, E, rp, h,
                                           fast ? hb : nullptr,
                                           W, fast ? wb : nullptr);

    if (fast) {
        agg_bf16<<<(NN + 3) / 4, 256, 0, stream>>>(hb, h0, edge_col, edge_vals, rp, io);
        lin_mfma<<<(NN + 63) / 64, 256, 0, stream>>>(io, wb, b, lptr);
    } else {
        agg_fp32<<<(NN + 3) / 4, 256, 0, stream>>>(h, h0, edge_col, edge_vals, rp, io);
        lin_kernel<<<(NN + RPB - 1) / RPB, 512, 0, stream>>>(io, W, b, lptr);
    }
}